// Round 1
// baseline (107.996 us; speedup 1.0000x reference)
//
#include <hip/hip_runtime.h>
#include <math.h>

#define G 64
#define GG 4096           // G*G
#define C 768
#define B 32
#define LR 0.01f
#define CUTOFF 0.001f

// ---------------------------------------------------------------------------
// Kernel 1: feat_dist[b][u] = sum_c (units[u][c] - x[b][c])^2
// 4 units per block, 64 threads (1 wave). Each lane owns channels
// c = 4*lane + 256*k (k=0..2) as float4. Per-b wave butterfly reduce.
// ---------------------------------------------------------------------------
__global__ __launch_bounds__(64) void som_dist(const float* __restrict__ x,
                                               const float* __restrict__ units,
                                               float* __restrict__ dist) {
    const int u0 = blockIdx.x * 4;
    const int lane = threadIdx.x;

    float4 uv[4][3];
#pragma unroll
    for (int u = 0; u < 4; ++u)
#pragma unroll
        for (int k = 0; k < 3; ++k)
            uv[u][k] = *(const float4*)(units + (size_t)(u0 + u) * C + 4 * lane + 256 * k);

    for (int b = 0; b < B; ++b) {
        float4 xv[3];
#pragma unroll
        for (int k = 0; k < 3; ++k)
            xv[k] = *(const float4*)(x + (size_t)b * C + 4 * lane + 256 * k);

        float acc0 = 0.f, acc1 = 0.f, acc2 = 0.f, acc3 = 0.f;
#pragma unroll
        for (int k = 0; k < 3; ++k) {
            float d;
            d = uv[0][k].x - xv[k].x; acc0 += d * d;
            d = uv[0][k].y - xv[k].y; acc0 += d * d;
            d = uv[0][k].z - xv[k].z; acc0 += d * d;
            d = uv[0][k].w - xv[k].w; acc0 += d * d;
            d = uv[1][k].x - xv[k].x; acc1 += d * d;
            d = uv[1][k].y - xv[k].y; acc1 += d * d;
            d = uv[1][k].z - xv[k].z; acc1 += d * d;
            d = uv[1][k].w - xv[k].w; acc1 += d * d;
            d = uv[2][k].x - xv[k].x; acc2 += d * d;
            d = uv[2][k].y - xv[k].y; acc2 += d * d;
            d = uv[2][k].z - xv[k].z; acc2 += d * d;
            d = uv[2][k].w - xv[k].w; acc2 += d * d;
            d = uv[3][k].x - xv[k].x; acc3 += d * d;
            d = uv[3][k].y - xv[k].y; acc3 += d * d;
            d = uv[3][k].z - xv[k].z; acc3 += d * d;
            d = uv[3][k].w - xv[k].w; acc3 += d * d;
        }
#pragma unroll
        for (int off = 32; off; off >>= 1) {
            acc0 += __shfl_xor(acc0, off);
            acc1 += __shfl_xor(acc1, off);
            acc2 += __shfl_xor(acc2, off);
            acc3 += __shfl_xor(acc3, off);
        }
        if (lane == 0) {
            dist[(size_t)b * GG + u0 + 0] = acc0;
            dist[(size_t)b * GG + u0 + 1] = acc1;
            dist[(size_t)b * GG + u0 + 2] = acc2;
            dist[(size_t)b * GG + u0 + 3] = acc3;
        }
    }
}

// ---------------------------------------------------------------------------
// Kernel 2: bmu[b] = argmin_u dist[b][u], first-occurrence tie rule.
// dist >= 0 so the float bit pattern is order-preserving; pack
// (bits << 32) | idx and take the u64 min.
// ---------------------------------------------------------------------------
__global__ __launch_bounds__(256) void som_argmin(const float* __restrict__ dist,
                                                  int* __restrict__ bmu) {
    const int b = blockIdx.x;
    const int t = threadIdx.x;

    unsigned long long best = ~0ull;
    for (int i = t; i < GG; i += 256) {
        unsigned int bits = __float_as_uint(dist[(size_t)b * GG + i]);
        unsigned long long key = ((unsigned long long)bits << 32) | (unsigned int)i;
        best = best < key ? best : key;
    }
#pragma unroll
    for (int off = 32; off; off >>= 1) {
        unsigned long long o = __shfl_xor(best, off);
        best = best < o ? best : o;
    }
    __shared__ unsigned long long s[4];
    if ((t & 63) == 0) s[t >> 6] = best;
    __syncthreads();
    if (t == 0) {
        unsigned long long m01 = s[0] < s[1] ? s[0] : s[1];
        unsigned long long m23 = s[2] < s[3] ? s[2] : s[3];
        unsigned long long m = m01 < m23 ? m01 : m23;
        bmu[b] = (int)(m & 0xffffffffu);
    }
}

// ---------------------------------------------------------------------------
// Kernel 3: out[u][c] = units[u][c]*(1 - s*Sg[u]) + s * sum_b w[u][b]*x[b][c]
// where w[u][b] = gaussian (cutoff-zeroed), s = LR*temperature/B.
// 4 units per block, 256 threads, each thread owns 3 channels.
// ---------------------------------------------------------------------------
__global__ __launch_bounds__(256) void som_update(const float* __restrict__ x,
                                                  const float* __restrict__ units,
                                                  const int* __restrict__ bmu,
                                                  const int* __restrict__ t_ptr,
                                                  float* __restrict__ out) {
    const int u0 = blockIdx.x * 4;
    const int tid = threadIdx.x;

    const float tt = (float)t_ptr[0];
    const float deno = logf(64.0f) / 9000.0f;                 // ln(G)/(0.9*MAX_T)
    const float ksize = 64.0f * expf(-tt * deno);
    const float sigma = 0.3f * ((ksize - 1.0f) * 0.5f - 1.0f) + 0.8f;
    const float inv2s2 = 1.0f / (2.0f * sigma * sigma);
    const float temp = expf(-(tt * 2.0f) / 10000.0f);
    const float s = LR * temp / (float)B;

    __shared__ float w[4][B];
    __shared__ float Sg[4];
    if (tid < 4 * B) {
        const int u = tid >> 5, b = tid & 31;
        const int gu = u0 + u;
        const float gy = (float)(gu >> 6), gx = (float)(gu & 63);
        const int bm = bmu[b];
        const float by = (float)(bm >> 6), bx = (float)(bm & 63);
        const float pd = (gy - by) * (gy - by) + (gx - bx) * (gx - bx);
        float g = expf(-pd * inv2s2);
        if (g < CUTOFF) g = 0.0f;
        w[u][b] = g;
    }
    __syncthreads();
    if (tid < 4) {
        float sg = 0.f;
#pragma unroll
        for (int b = 0; b < B; ++b) sg += w[tid][b];
        Sg[tid] = sg;
    }
    __syncthreads();

#pragma unroll
    for (int k = 0; k < 3; ++k) {
        const int c = tid + 256 * k;
        float xb[B];
#pragma unroll
        for (int b = 0; b < B; ++b) xb[b] = x[(size_t)b * C + c];
#pragma unroll
        for (int u = 0; u < 4; ++u) {
            float acc = 0.f;
#pragma unroll
            for (int b = 0; b < B; ++b) acc += w[u][b] * xb[b];
            const int gu = u0 + u;
            const float uval = units[(size_t)gu * C + c];
            out[(size_t)gu * C + c] = uval * (1.0f - s * Sg[u]) + s * acc;
        }
    }
}

extern "C" void kernel_launch(void* const* d_in, const int* in_sizes, int n_in,
                              void* d_out, int out_size, void* d_ws, size_t ws_size,
                              hipStream_t stream) {
    const float* x = (const float*)d_in[0];      // [32,3,16,16] -> [32,768]
    const float* units = (const float*)d_in[1];  // [64,64,768]
    const int* t = (const int*)d_in[2];          // scalar step
    float* out = (float*)d_out;                  // [64,64,768] f32

    float* dist = (float*)d_ws;                                  // 32*4096 f32 = 512 KB
    int* bmu = (int*)((char*)d_ws + (size_t)GG * B * sizeof(float)); // 32 ints

    som_dist<<<GG / 4, 64, 0, stream>>>(x, units, dist);
    som_argmin<<<B, 256, 0, stream>>>(dist, bmu);
    som_update<<<GG / 4, 256, 0, stream>>>(x, units, bmu, t, out);
}

// Round 2
// 107.562 us; speedup vs baseline: 1.0040x; 1.0040x over previous
//
#include <hip/hip_runtime.h>
#include <math.h>

#define G 64
#define GG 4096           // G*G
#define C 768
#define B 32
#define LR 0.01f
#define CUTOFF 0.001f

// ws layout: gkeys[b*16] for b in 0..31, u64 each (128B stride -> distinct L2 lines)
#define KEY_STRIDE 16
#define KEY_BYTES (B * KEY_STRIDE * 8)

// ---------------------------------------------------------------------------
// Packed 4-accumulator wave reduction: returns S_{lane&3} in every lane
// (7 shfl instead of 24).
// ---------------------------------------------------------------------------
__device__ __forceinline__ float reduce4(float a0, float a1, float a2, float a3,
                                         int lane) {
    float r01 = ((lane & 1) ? a1 : a0) + __shfl_xor(((lane & 1) ? a0 : a1), 1);
    float r23 = ((lane & 1) ? a3 : a2) + __shfl_xor(((lane & 1) ? a2 : a3), 1);
    float r   = ((lane & 2) ? r23 : r01) + __shfl_xor(((lane & 2) ? r01 : r23), 2);
    r += __shfl_xor(r, 4);
    r += __shfl_xor(r, 8);
    r += __shfl_xor(r, 16);
    r += __shfl_xor(r, 32);
    return r;   // lane l holds full 64-lane sum of a_{l&3}
}

// ---------------------------------------------------------------------------
// Kernel 1: dist + argmin fused.
// 512 blocks x 256 threads. Block = 16 units x 16 batches.
// Wave w handles units u0+4w..u0+4w+3 for the block's 16 b's.
// Lane owns channels 4*lane + 256*k (k=0..2) as float4.
// Per (wave,b): packed reduce -> per-unit dist -> packed (bits<<32|idx) key
// -> 2-step u64 min -> LDS; block then atomicMin's one key per b.
// ---------------------------------------------------------------------------
__global__ __launch_bounds__(256) void som_dist_argmin(const float* __restrict__ x,
                                                       const float* __restrict__ units,
                                                       unsigned long long* __restrict__ gkeys) {
    const int ub = blockIdx.x >> 1;        // 0..255
    const int bh = blockIdx.x & 1;         // 0..1
    const int u0 = ub * 16;
    const int b0 = bh * 16;
    const int wv = threadIdx.x >> 6;       // 0..3
    const int lane = threadIdx.x & 63;
    const int uw = u0 + 4 * wv;            // this wave's first unit

    float4 uv[4][3];
#pragma unroll
    for (int u = 0; u < 4; ++u)
#pragma unroll
        for (int k = 0; k < 3; ++k)
            uv[u][k] = *(const float4*)(units + (size_t)(uw + u) * C + 4 * lane + 256 * k);

    __shared__ unsigned long long lkey[4][16];

#pragma unroll 4
    for (int bi = 0; bi < 16; ++bi) {
        const int b = b0 + bi;
        float4 xv[3];
#pragma unroll
        for (int k = 0; k < 3; ++k)
            xv[k] = *(const float4*)(x + (size_t)b * C + 4 * lane + 256 * k);

        float a0 = 0.f, a1 = 0.f, a2 = 0.f, a3 = 0.f;
#pragma unroll
        for (int k = 0; k < 3; ++k) {
            float d;
            d = uv[0][k].x - xv[k].x; a0 += d * d;
            d = uv[0][k].y - xv[k].y; a0 += d * d;
            d = uv[0][k].z - xv[k].z; a0 += d * d;
            d = uv[0][k].w - xv[k].w; a0 += d * d;
            d = uv[1][k].x - xv[k].x; a1 += d * d;
            d = uv[1][k].y - xv[k].y; a1 += d * d;
            d = uv[1][k].z - xv[k].z; a1 += d * d;
            d = uv[1][k].w - xv[k].w; a1 += d * d;
            d = uv[2][k].x - xv[k].x; a2 += d * d;
            d = uv[2][k].y - xv[k].y; a2 += d * d;
            d = uv[2][k].z - xv[k].z; a2 += d * d;
            d = uv[2][k].w - xv[k].w; a2 += d * d;
            d = uv[3][k].x - xv[k].x; a3 += d * d;
            d = uv[3][k].y - xv[k].y; a3 += d * d;
            d = uv[3][k].z - xv[k].z; a3 += d * d;
            d = uv[3][k].w - xv[k].w; a3 += d * d;
        }
        const float s = reduce4(a0, a1, a2, a3, lane);   // dist of unit uw+(lane&3)

        unsigned long long key =
            ((unsigned long long)__float_as_uint(s) << 32) |
            (unsigned int)(uw + (lane & 3));
        unsigned long long o;
        o = __shfl_xor(key, 1); key = key < o ? key : o;
        o = __shfl_xor(key, 2); key = key < o ? key : o;
        if (lane == 0) lkey[wv][bi] = key;               // wave min over its 4 units
    }
    __syncthreads();

    if (threadIdx.x < 16) {
        unsigned long long k0 = lkey[0][threadIdx.x];
        unsigned long long k1 = lkey[1][threadIdx.x];
        unsigned long long k2 = lkey[2][threadIdx.x];
        unsigned long long k3 = lkey[3][threadIdx.x];
        unsigned long long m01 = k0 < k1 ? k0 : k1;
        unsigned long long m23 = k2 < k3 ? k2 : k3;
        unsigned long long m = m01 < m23 ? m01 : m23;
        atomicMin(&gkeys[(size_t)(b0 + threadIdx.x) * KEY_STRIDE], m);
    }
}

// ---------------------------------------------------------------------------
// Kernel 2: out[u][c] = units[u][c]*(1 - s*Sg[u]) + s * sum_b w[u][b]*x[b][c]
// 8 units/block, 512 blocks x 256 threads, each thread owns 3 channels.
// ---------------------------------------------------------------------------
__global__ __launch_bounds__(256) void som_update(const float* __restrict__ x,
                                                  const float* __restrict__ units,
                                                  const unsigned long long* __restrict__ gkeys,
                                                  const int* __restrict__ t_ptr,
                                                  float* __restrict__ out) {
    const int u0 = blockIdx.x * 8;
    const int tid = threadIdx.x;

    const float tt = (float)t_ptr[0];
    const float deno = logf(64.0f) / 9000.0f;                 // ln(G)/(0.9*MAX_T)
    const float ksize = 64.0f * expf(-tt * deno);
    const float sigma = 0.3f * ((ksize - 1.0f) * 0.5f - 1.0f) + 0.8f;
    const float inv2s2 = 1.0f / (2.0f * sigma * sigma);
    const float temp = expf(-(tt * 2.0f) / 10000.0f);
    const float s = LR * temp / (float)B;

    __shared__ float by_s[B], bx_s[B];
    __shared__ float w[8][B];
    __shared__ float Sg[8];

    if (tid < B) {
        const int idx = (int)(gkeys[(size_t)tid * KEY_STRIDE] & 0xffffffffu);
        by_s[tid] = (float)(idx >> 6);
        bx_s[tid] = (float)(idx & 63);
    }
    __syncthreads();

    {   // 8 units x 32 b == 256 threads exactly
        const int u = tid >> 5, b = tid & 31;
        const int gu = u0 + u;
        const float gy = (float)(gu >> 6), gx = (float)(gu & 63);
        const float dy = gy - by_s[b], dx = gx - bx_s[b];
        float g = expf(-(dy * dy + dx * dx) * inv2s2);
        if (g < CUTOFF) g = 0.0f;
        w[u][b] = g;
    }
    __syncthreads();
    if (tid < 8) {
        float sg = 0.f;
#pragma unroll
        for (int b = 0; b < B; ++b) sg += w[tid][b];
        Sg[tid] = sg;
    }
    __syncthreads();

#pragma unroll
    for (int k = 0; k < 3; ++k) {
        const int c = tid + 256 * k;
        float xb[B];
#pragma unroll
        for (int b = 0; b < B; ++b) xb[b] = x[(size_t)b * C + c];
#pragma unroll
        for (int u = 0; u < 8; ++u) {
            float acc = 0.f;
#pragma unroll
            for (int b = 0; b < B; ++b) acc += w[u][b] * xb[b];
            const int gu = u0 + u;
            const float uval = units[(size_t)gu * C + c];
            out[(size_t)gu * C + c] = uval * (1.0f - s * Sg[u]) + s * acc;
        }
    }
}

extern "C" void kernel_launch(void* const* d_in, const int* in_sizes, int n_in,
                              void* d_out, int out_size, void* d_ws, size_t ws_size,
                              hipStream_t stream) {
    const float* x = (const float*)d_in[0];      // [32,3,16,16] -> [32,768]
    const float* units = (const float*)d_in[1];  // [64,64,768]
    const int* t = (const int*)d_in[2];          // scalar step
    float* out = (float*)d_out;                  // [64,64,768] f32

    unsigned long long* gkeys = (unsigned long long*)d_ws;

    // init keys to u64-max so packed (dist_bits<<32|idx) atomicMin works
    hipMemsetAsync(gkeys, 0xFF, KEY_BYTES, stream);
    som_dist_argmin<<<512, 256, 0, stream>>>(x, units, gkeys);
    som_update<<<512, 256, 0, stream>>>(x, units, gkeys, t, out);
}

// Round 3
// 106.976 us; speedup vs baseline: 1.0095x; 1.0055x over previous
//
#include <hip/hip_runtime.h>
#include <math.h>

#define G 64
#define GG 4096           // G*G
#define C 768
#define B 32
#define LR 0.01f
#define CUTOFF 0.001f

// ws layout: pkeys[b][ub], b in 0..31, ub in 0..255 — per-(batch, unit-block-of-16)
// partial min keys, u64 each. 64 KB total. Written entirely by kernel A before
// kernel B reads it -> no initialization needed (no atomics, no memset).
#define NUB 256

// ---------------------------------------------------------------------------
// Packed 4-accumulator wave reduction: lane l ends with the full 64-lane sum
// of a_{l&3} (7 shfl instead of 24).
// ---------------------------------------------------------------------------
__device__ __forceinline__ float reduce4(float a0, float a1, float a2, float a3,
                                         int lane) {
    float r01 = ((lane & 1) ? a1 : a0) + __shfl_xor(((lane & 1) ? a0 : a1), 1);
    float r23 = ((lane & 1) ? a3 : a2) + __shfl_xor(((lane & 1) ? a2 : a3), 1);
    float r   = ((lane & 2) ? r23 : r01) + __shfl_xor(((lane & 2) ? r01 : r23), 2);
    r += __shfl_xor(r, 4);
    r += __shfl_xor(r, 8);
    r += __shfl_xor(r, 16);
    r += __shfl_xor(r, 32);
    return r;
}

// ---------------------------------------------------------------------------
// Kernel A: dist + per-block partial argmin.
// 512 blocks x 256 threads. Block = 16 units x 16 batches.
// Wave w owns units u0+4w..u0+4w+3; lane owns channels 4*lane + 256*k.
// Per (wave,b): packed reduce -> per-unit dist -> (bits<<32|idx) key ->
// 2-step u64 min -> LDS; block writes one partial key per b to pkeys[b][ub].
// ---------------------------------------------------------------------------
__global__ __launch_bounds__(256) void som_dist_part(const float* __restrict__ x,
                                                     const float* __restrict__ units,
                                                     unsigned long long* __restrict__ pkeys) {
    const int ub = blockIdx.x >> 1;        // 0..255 (unit block of 16)
    const int bh = blockIdx.x & 1;         // 0..1   (batch half)
    const int u0 = ub * 16;
    const int b0 = bh * 16;
    const int wv = threadIdx.x >> 6;       // 0..3
    const int lane = threadIdx.x & 63;
    const int uw = u0 + 4 * wv;

    float4 uv[4][3];
#pragma unroll
    for (int u = 0; u < 4; ++u)
#pragma unroll
        for (int k = 0; k < 3; ++k)
            uv[u][k] = *(const float4*)(units + (size_t)(uw + u) * C + 4 * lane + 256 * k);

    __shared__ unsigned long long lkey[4][16];

#pragma unroll 4
    for (int bi = 0; bi < 16; ++bi) {
        const int b = b0 + bi;
        float4 xv[3];
#pragma unroll
        for (int k = 0; k < 3; ++k)
            xv[k] = *(const float4*)(x + (size_t)b * C + 4 * lane + 256 * k);

        float a0 = 0.f, a1 = 0.f, a2 = 0.f, a3 = 0.f;
#pragma unroll
        for (int k = 0; k < 3; ++k) {
            float d;
            d = uv[0][k].x - xv[k].x; a0 += d * d;
            d = uv[0][k].y - xv[k].y; a0 += d * d;
            d = uv[0][k].z - xv[k].z; a0 += d * d;
            d = uv[0][k].w - xv[k].w; a0 += d * d;
            d = uv[1][k].x - xv[k].x; a1 += d * d;
            d = uv[1][k].y - xv[k].y; a1 += d * d;
            d = uv[1][k].z - xv[k].z; a1 += d * d;
            d = uv[1][k].w - xv[k].w; a1 += d * d;
            d = uv[2][k].x - xv[k].x; a2 += d * d;
            d = uv[2][k].y - xv[k].y; a2 += d * d;
            d = uv[2][k].z - xv[k].z; a2 += d * d;
            d = uv[2][k].w - xv[k].w; a2 += d * d;
            d = uv[3][k].x - xv[k].x; a3 += d * d;
            d = uv[3][k].y - xv[k].y; a3 += d * d;
            d = uv[3][k].z - xv[k].z; a3 += d * d;
            d = uv[3][k].w - xv[k].w; a3 += d * d;
        }
        const float s = reduce4(a0, a1, a2, a3, lane);   // dist of unit uw+(lane&3)

        unsigned long long key =
            ((unsigned long long)__float_as_uint(s) << 32) |
            (unsigned int)(uw + (lane & 3));
        unsigned long long o;
        o = __shfl_xor(key, 1); key = key < o ? key : o;
        o = __shfl_xor(key, 2); key = key < o ? key : o;
        if (lane == 0) lkey[wv][bi] = key;               // wave min over its 4 units
    }
    __syncthreads();

    if (threadIdx.x < 16) {
        unsigned long long k0 = lkey[0][threadIdx.x];
        unsigned long long k1 = lkey[1][threadIdx.x];
        unsigned long long k2 = lkey[2][threadIdx.x];
        unsigned long long k3 = lkey[3][threadIdx.x];
        unsigned long long m01 = k0 < k1 ? k0 : k1;
        unsigned long long m23 = k2 < k3 ? k2 : k3;
        unsigned long long m = m01 < m23 ? m01 : m23;
        pkeys[(size_t)(b0 + threadIdx.x) * NUB + ub] = m;
    }
}

// ---------------------------------------------------------------------------
// Kernel B: final argmin reduce (per block, L2-resident 64 KB) + update.
// out[u][c] = units[u][c]*(1 - s*Sg[u]) + s * sum_b w[u][b]*x[b][c]
// 8 units/block, 512 blocks x 256 threads, each thread owns 3 channels.
// ---------------------------------------------------------------------------
__global__ __launch_bounds__(256) void som_update(const float* __restrict__ x,
                                                  const float* __restrict__ units,
                                                  const unsigned long long* __restrict__ pkeys,
                                                  const int* __restrict__ t_ptr,
                                                  float* __restrict__ out) {
    const int u0 = blockIdx.x * 8;
    const int tid = threadIdx.x;

    const float tt = (float)t_ptr[0];
    const float deno = logf(64.0f) / 9000.0f;                 // ln(G)/(0.9*MAX_T)
    const float ksize = 64.0f * expf(-tt * deno);
    const float sigma = 0.3f * ((ksize - 1.0f) * 0.5f - 1.0f) + 0.8f;
    const float inv2s2 = 1.0f / (2.0f * sigma * sigma);
    const float temp = expf(-(tt * 2.0f) / 10000.0f);
    const float s = LR * temp / (float)B;

    __shared__ unsigned long long part[B][8];
    __shared__ float by_s[B], bx_s[B];
    __shared__ float w[8][B];
    __shared__ float Sg[8];

    // --- argmin final reduce: 256 threads = 32 b x 8 chunks of 32 keys ---
    {
        const int b = tid >> 3, ch = tid & 7;
        const unsigned long long* p = pkeys + (size_t)b * NUB + ch * 32;
        unsigned long long m = p[0];
#pragma unroll
        for (int j = 1; j < 32; ++j) {
            unsigned long long k = p[j];
            m = m < k ? m : k;
        }
        part[b][ch] = m;
    }
    __syncthreads();
    if (tid < B) {
        unsigned long long m = part[tid][0];
#pragma unroll
        for (int j = 1; j < 8; ++j) {
            unsigned long long k = part[tid][j];
            m = m < k ? m : k;
        }
        const int idx = (int)(m & 0xffffffffu);
        by_s[tid] = (float)(idx >> 6);
        bx_s[tid] = (float)(idx & 63);
    }
    __syncthreads();

    {   // gaussian weights: 8 units x 32 b == 256 threads exactly
        const int u = tid >> 5, b = tid & 31;
        const int gu = u0 + u;
        const float gy = (float)(gu >> 6), gx = (float)(gu & 63);
        const float dy = gy - by_s[b], dx = gx - bx_s[b];
        float g = expf(-(dy * dy + dx * dx) * inv2s2);
        if (g < CUTOFF) g = 0.0f;
        w[u][b] = g;
    }
    __syncthreads();
    if (tid < 8) {
        float sg = 0.f;
#pragma unroll
        for (int b = 0; b < B; ++b) sg += w[tid][b];
        Sg[tid] = sg;
    }
    __syncthreads();

#pragma unroll
    for (int k = 0; k < 3; ++k) {
        const int c = tid + 256 * k;
        float xb[B];
#pragma unroll
        for (int b = 0; b < B; ++b) xb[b] = x[(size_t)b * C + c];
#pragma unroll
        for (int u = 0; u < 8; ++u) {
            float acc = 0.f;
#pragma unroll
            for (int b = 0; b < B; ++b) acc += w[u][b] * xb[b];
            const int gu = u0 + u;
            const float uval = units[(size_t)gu * C + c];
            out[(size_t)gu * C + c] = uval * (1.0f - s * Sg[u]) + s * acc;
        }
    }
}

extern "C" void kernel_launch(void* const* d_in, const int* in_sizes, int n_in,
                              void* d_out, int out_size, void* d_ws, size_t ws_size,
                              hipStream_t stream) {
    const float* x = (const float*)d_in[0];      // [32,3,16,16] -> [32,768]
    const float* units = (const float*)d_in[1];  // [64,64,768]
    const int* t = (const int*)d_in[2];          // scalar step
    float* out = (float*)d_out;                  // [64,64,768] f32

    unsigned long long* pkeys = (unsigned long long*)d_ws;   // [32][256] u64 = 64 KB

    som_dist_part<<<512, 256, 0, stream>>>(x, units, pkeys);
    som_update<<<512, 256, 0, stream>>>(x, units, pkeys, t, out);
}

// Round 4
// 93.143 us; speedup vs baseline: 1.1595x; 1.1485x over previous
//
#include <hip/hip_runtime.h>
#include <math.h>

#define G 64
#define GG 4096           // G*G
#define C 768
#define B 32
#define LR 0.01f
#define CUTOFF 0.001f

// ws layout: pkeys[b][ub], b in 0..31, ub in 0..255 — per-(batch, unit-block-of-16)
// partial min keys, u64 each. 64 KB total. Written entirely by kernel A before
// kernel B reads it -> no initialization needed (no atomics, no memset).
#define NUB 256

// ---------------------------------------------------------------------------
// Packed 4-accumulator wave reduction: lane l ends with the full 64-lane sum
// of a_{l&3} (7 shfl instead of 24).
// ---------------------------------------------------------------------------
__device__ __forceinline__ float reduce4(float a0, float a1, float a2, float a3,
                                         int lane) {
    float r01 = ((lane & 1) ? a1 : a0) + __shfl_xor(((lane & 1) ? a0 : a1), 1);
    float r23 = ((lane & 1) ? a3 : a2) + __shfl_xor(((lane & 1) ? a2 : a3), 1);
    float r   = ((lane & 2) ? r23 : r01) + __shfl_xor(((lane & 2) ? r01 : r23), 2);
    r += __shfl_xor(r, 4);
    r += __shfl_xor(r, 8);
    r += __shfl_xor(r, 16);
    r += __shfl_xor(r, 32);
    return r;
}

// ---------------------------------------------------------------------------
// Kernel A: dist + per-block partial argmin.  (unchanged from round 3 — near
// its 2.6 µs VALU floor)
// 512 blocks x 256 threads. Block = 16 units x 16 batches.
// ---------------------------------------------------------------------------
__global__ __launch_bounds__(256) void som_dist_part(const float* __restrict__ x,
                                                     const float* __restrict__ units,
                                                     unsigned long long* __restrict__ pkeys) {
    const int ub = blockIdx.x >> 1;        // 0..255 (unit block of 16)
    const int bh = blockIdx.x & 1;         // 0..1   (batch half)
    const int u0 = ub * 16;
    const int b0 = bh * 16;
    const int wv = threadIdx.x >> 6;       // 0..3
    const int lane = threadIdx.x & 63;
    const int uw = u0 + 4 * wv;

    float4 uv[4][3];
#pragma unroll
    for (int u = 0; u < 4; ++u)
#pragma unroll
        for (int k = 0; k < 3; ++k)
            uv[u][k] = *(const float4*)(units + (size_t)(uw + u) * C + 4 * lane + 256 * k);

    __shared__ unsigned long long lkey[4][16];

#pragma unroll 4
    for (int bi = 0; bi < 16; ++bi) {
        const int b = b0 + bi;
        float4 xv[3];
#pragma unroll
        for (int k = 0; k < 3; ++k)
            xv[k] = *(const float4*)(x + (size_t)b * C + 4 * lane + 256 * k);

        float a0 = 0.f, a1 = 0.f, a2 = 0.f, a3 = 0.f;
#pragma unroll
        for (int k = 0; k < 3; ++k) {
            float d;
            d = uv[0][k].x - xv[k].x; a0 += d * d;
            d = uv[0][k].y - xv[k].y; a0 += d * d;
            d = uv[0][k].z - xv[k].z; a0 += d * d;
            d = uv[0][k].w - xv[k].w; a0 += d * d;
            d = uv[1][k].x - xv[k].x; a1 += d * d;
            d = uv[1][k].y - xv[k].y; a1 += d * d;
            d = uv[1][k].z - xv[k].z; a1 += d * d;
            d = uv[1][k].w - xv[k].w; a1 += d * d;
            d = uv[2][k].x - xv[k].x; a2 += d * d;
            d = uv[2][k].y - xv[k].y; a2 += d * d;
            d = uv[2][k].z - xv[k].z; a2 += d * d;
            d = uv[2][k].w - xv[k].w; a2 += d * d;
            d = uv[3][k].x - xv[k].x; a3 += d * d;
            d = uv[3][k].y - xv[k].y; a3 += d * d;
            d = uv[3][k].z - xv[k].z; a3 += d * d;
            d = uv[3][k].w - xv[k].w; a3 += d * d;
        }
        const float s = reduce4(a0, a1, a2, a3, lane);   // dist of unit uw+(lane&3)

        unsigned long long key =
            ((unsigned long long)__float_as_uint(s) << 32) |
            (unsigned int)(uw + (lane & 3));
        unsigned long long o;
        o = __shfl_xor(key, 1); key = key < o ? key : o;
        o = __shfl_xor(key, 2); key = key < o ? key : o;
        if (lane == 0) lkey[wv][bi] = key;               // wave min over its 4 units
    }
    __syncthreads();

    if (threadIdx.x < 16) {
        unsigned long long k0 = lkey[0][threadIdx.x];
        unsigned long long k1 = lkey[1][threadIdx.x];
        unsigned long long k2 = lkey[2][threadIdx.x];
        unsigned long long k3 = lkey[3][threadIdx.x];
        unsigned long long m01 = k0 < k1 ? k0 : k1;
        unsigned long long m23 = k2 < k3 ? k2 : k3;
        unsigned long long m = m01 < m23 ? m01 : m23;
        pkeys[(size_t)(b0 + threadIdx.x) * NUB + ub] = m;
    }
}

// ---------------------------------------------------------------------------
// Kernel B: final argmin reduce + update, loop-reordered.
// Main loop is b-outer / u-inner: per b one coalesced x load per channel and
// ONE ds_read broadcast of w[u][b] feeding 3 FMAs (1.33 instr/FMA vs 2.0 in
// round 3's k-outer order, which re-read w per k). Accumulation order over b
// is unchanged -> bit-compatible rounding with the passing round-3 kernel.
// 8 units/block, 512 blocks x 256 threads, thread owns channels c, c+256, c+512.
// ---------------------------------------------------------------------------
__global__ __launch_bounds__(256) void som_update(const float* __restrict__ x,
                                                  const float* __restrict__ units,
                                                  const unsigned long long* __restrict__ pkeys,
                                                  const int* __restrict__ t_ptr,
                                                  float* __restrict__ out) {
    const int u0 = blockIdx.x * 8;
    const int tid = threadIdx.x;

    const float tt = (float)t_ptr[0];
    const float deno = logf(64.0f) / 9000.0f;                 // ln(G)/(0.9*MAX_T)
    const float ksize = 64.0f * expf(-tt * deno);
    const float sigma = 0.3f * ((ksize - 1.0f) * 0.5f - 1.0f) + 0.8f;
    const float inv2s2 = 1.0f / (2.0f * sigma * sigma);
    const float temp = expf(-(tt * 2.0f) / 10000.0f);
    const float s = LR * temp / (float)B;

    __shared__ unsigned long long part[B][8];
    __shared__ float by_s[B], bx_s[B];
    __shared__ float w[8][B];
    __shared__ float Sg[8];

    // --- argmin final reduce: 256 threads = 32 b x 8 chunks of 32 keys ---
    {
        const int b = tid >> 3, ch = tid & 7;
        const unsigned long long* p = pkeys + (size_t)b * NUB + ch * 32;
        unsigned long long m = p[0];
#pragma unroll
        for (int j = 1; j < 32; ++j) {
            unsigned long long k = p[j];
            m = m < k ? m : k;
        }
        part[b][ch] = m;
    }
    __syncthreads();
    if (tid < B) {
        unsigned long long m = part[tid][0];
#pragma unroll
        for (int j = 1; j < 8; ++j) {
            unsigned long long k = part[tid][j];
            m = m < k ? m : k;
        }
        const int idx = (int)(m & 0xffffffffu);
        by_s[tid] = (float)(idx >> 6);
        bx_s[tid] = (float)(idx & 63);
    }
    __syncthreads();

    {   // gaussian weights: 8 units x 32 b == 256 threads exactly
        const int u = tid >> 5, b = tid & 31;
        const int gu = u0 + u;
        const float gy = (float)(gu >> 6), gx = (float)(gu & 63);
        const float dy = gy - by_s[b], dx = gx - bx_s[b];
        float g = expf(-(dy * dy + dx * dx) * inv2s2);
        if (g < CUTOFF) g = 0.0f;
        w[u][b] = g;
    }
    __syncthreads();
    if (tid < 8) {
        float sg = 0.f;
#pragma unroll
        for (int b = 0; b < B; ++b) sg += w[tid][b];
        Sg[tid] = sg;
    }
    __syncthreads();

    // --- main accumulation: b-outer, u-inner, 3 channels per thread ---
    float acc[8][3];
#pragma unroll
    for (int u = 0; u < 8; ++u)
#pragma unroll
        for (int k = 0; k < 3; ++k) acc[u][k] = 0.f;

    for (int b = 0; b < B; ++b) {
        const float x0 = x[(size_t)b * C + tid];
        const float x1 = x[(size_t)b * C + tid + 256];
        const float x2 = x[(size_t)b * C + tid + 512];
#pragma unroll
        for (int u = 0; u < 8; ++u) {
            const float wv = w[u][b];            // wave-uniform LDS broadcast
            acc[u][0] = fmaf(wv, x0, acc[u][0]);
            acc[u][1] = fmaf(wv, x1, acc[u][1]);
            acc[u][2] = fmaf(wv, x2, acc[u][2]);
        }
    }

#pragma unroll
    for (int u = 0; u < 8; ++u) {
        const int gu = u0 + u;
        const float f = 1.0f - s * Sg[u];
        out[(size_t)gu * C + tid      ] = units[(size_t)gu * C + tid      ] * f + s * acc[u][0];
        out[(size_t)gu * C + tid + 256] = units[(size_t)gu * C + tid + 256] * f + s * acc[u][1];
        out[(size_t)gu * C + tid + 512] = units[(size_t)gu * C + tid + 512] * f + s * acc[u][2];
    }
}

extern "C" void kernel_launch(void* const* d_in, const int* in_sizes, int n_in,
                              void* d_out, int out_size, void* d_ws, size_t ws_size,
                              hipStream_t stream) {
    const float* x = (const float*)d_in[0];      // [32,3,16,16] -> [32,768]
    const float* units = (const float*)d_in[1];  // [64,64,768]
    const int* t = (const int*)d_in[2];          // scalar step
    float* out = (float*)d_out;                  // [64,64,768] f32

    unsigned long long* pkeys = (unsigned long long*)d_ws;   // [32][256] u64 = 64 KB

    som_dist_part<<<512, 256, 0, stream>>>(x, units, pkeys);
    som_update<<<512, 256, 0, stream>>>(x, units, pkeys, t, out);
}